// Round 10
// baseline (295.148 us; speedup 1.0000x reference)
//
#include <hip/hip_runtime.h>

#define DIM   128
#define DMASK 127
#define PLANE (DIM * DIM)     // 16384
#define VOX   (1 << 21)       // 128^3
#define NCH   12

typedef __attribute__((ext_vector_type(2))) _Float16 half2v;

// Per-channel shift pairs (d,h,w) = 2*(one_hot_idx - 1); verified (absmax 0).
__constant__ int c_sd1[12] = { 0, 0, 0, 0, 0, 2, 2, 2, 0, 0, 0, 0};
__constant__ int c_sh1[12] = { 0,-2,-2, 0, 0, 0, 0, 0, 2, 2, 2, 2};
__constant__ int c_sw1[12] = {-2, 0, 0, 2, 2, 0, 0, 0, 0, 0, 0, 0};
__constant__ int c_sd2[12] = {-2,-2, 0,-2, 0, 0, 0, 0,-2, 0, 0, 2};
__constant__ int c_sh2[12] = { 0, 0, 0, 0,-2, 0,-2, 0, 0, 0, 0, 0};
__constant__ int c_sw2[12] = { 0, 0,-2, 0, 0,-2, 0, 2, 0,-2, 2, 0};

__device__ __forceinline__ int clamp7(int v) { return min(max(v, 0), DMASK); }

// DPP wave-shift cross-lane: VALU-pipe, no DS unit. old-operand doubles as
// the boundary fix (bound_ctrl=false -> invalid source lane keeps old).
// HW-validated r7/r8/r9 (absmax 0.0; r8: VALUBusy 57->67).
__device__ __forceinline__ float dpp_shr1(float old_, float src) {
    return __int_as_float(__builtin_amdgcn_update_dpp(
        __float_as_int(old_), __float_as_int(src), 0x138, 0xF, 0xF, false));
}
__device__ __forceinline__ float dpp_shl1(float old_, float src) {
    return __int_as_float(__builtin_amdgcn_update_dpp(
        __float_as_int(old_), __float_as_int(src), 0x130, 0xF, 0xF, false));
}

// FFUSE v5 (r10): 8-row x 8-plane tiles — spend the 1-block/CU budget on
// LESS HALO REDUNDANCY. LEDGER:
//  - NEVER pass min-waves to __launch_bounds__ (r1/r7: forced-VGPR spill).
//  - Fusion validated (r6/r8): WRITE 96MB -> ~8B, FETCH = input footprint.
//  - DPP validated (r8).
//  - r9: 768-thread blocks DO NOT co-reside (512 blocks, VGPR 76, LDS 97KB
//    -> Occ still 33% = 1 block/CU) => 1 block/CU is the regime. Therefore:
//    spend VGPR up to the 3-wave/SIMD launch cap (<=168) and LDS freely.
//  - This round: t-row redundancy (R+4)/R: R=4 -> 2.0x, R=8 -> 1.5x.
//    8-row x 8-plane: 16x16 = 256 blocks (1/CU exactly), 12 iters/block,
//    barriers 16 -> 8, pipe work x0.9, reduce total unchanged.
//  - GATE: VGPR must be <= 168 with no scratch (WRITE stays ~bytes). If
//    >= 170 the compiler is spill-capping (launchability) -> revert.
// Structure: 256 blocks x 768 threads (12 waves, wave = channel, both
// images). Per plane: 12 t-rows -> H-box slide -> 8-row D-window update;
// f16 SSD rows -> double-buffered 96KB LDS; 1 barrier; 8 of 12 waves
// (rotating) run the kmse math on one row each.

#define STREAM_PIPE(IMC, WIN, HIST, IMGI, S5C)                               \
    {                                                                        \
        float tX[12], tY[12];                                                \
        _Pragma("unroll")                                                    \
        for (int r = 0; r < 12; ++r) {                                       \
            float2 a = *(const float2*)(IMC + (pOffA + rowOffA[r] + colA));  \
            float2 b = *(const float2*)(IMC + (pOffB + rowOffB[r] + colB));  \
            a.y = fixAlo ? a.x : a.y;  a.x = fixAhi ? a.y : a.x;             \
            b.y = fixBlo ? b.x : b.y;  b.x = fixBhi ? b.y : b.x;             \
            float dx = a.x - b.x; dx *= dx;      /* D2[2l]   */              \
            float dy = a.y - b.y; dy *= dy;      /* D2[2l+1] */              \
            float lx = dpp_shr1(dx, dx);         /* D2[2l-2]; l0->dx */      \
            float ly = dpp_shr1(dx, dy);         /* D2[2l-1]; l0->dx */      \
            float rx = dpp_shl1(dy, dx);         /* D2[2l+2]; l63->dy */     \
            float ry = dpp_shl1(dy, dy);         /* D2[2l+3]; l63->dy */     \
            float m = ly + dx + dy + rx;                                     \
            tX[r] = lx + m;                      /* W-box(2l)   */           \
            tY[r] = m + ry;                      /* W-box(2l+1) */           \
        }                                                                    \
        float sx = tX[0] + tX[1] + tX[2] + tX[3] + tX[4];                    \
        float sy = tY[0] + tY[1] + tY[2] + tY[3] + tY[4];                    \
        _Pragma("unroll")                                                    \
        for (int k = 0; k < 8; ++k) {                                        \
            half2v hv = { (_Float16)sx, (_Float16)sy }; /* round first */    \
            half2v old = HIST[S5C][k];                                       \
            WIN[k].x += (float)hv[0] - (float)old[0];                        \
            WIN[k].y += (float)hv[1] - (float)old[1];                        \
            HIST[S5C][k] = hv;                                               \
            if (dowrite) {                                                   \
                half2v ov = { (_Float16)WIN[k].x, (_Float16)WIN[k].y };      \
                sb[bb][ch][IMGI][k][l] = ov;                                 \
            }                                                                \
            if (k < 7) {                                                     \
                sx += tX[k + 5] - tX[k];                                     \
                sy += tY[k + 5] - tY[k];                                     \
            }                                                                \
        }                                                                    \
    }

// One full plane iteration (both streams + optional barrier/reduce).
// Reducer rotation: offsets 0,4,8 cycle with it; waves with rr<8 handle
// row rr (5-6 reduces per wave over the 8 dowrite iters).
#define PLANE_ITER(IT_EXPR, S5C)                                             \
    {                                                                        \
        int it = (IT_EXPR);                                                  \
        int dp = clamp7(d0 - 2 + it);                                        \
        int pOffA = clamp7(dp + sd1) * (PLANE * 4);                          \
        int pOffB = clamp7(dp + sd2) * (PLANE * 4);                          \
        bool dowrite = (it >= 4);                                            \
        int bb = it & 1;                                                     \
        STREAM_PIPE(im0, win0, hist0, 0, S5C)                                \
        STREAM_PIPE(im1, win1, hist1, 1, S5C)                                \
        if (dowrite) {                                                       \
            __syncthreads();                                                 \
            int off = ((it - 4) % 3) << 2;                                   \
            int rr = wv - off; if (rr < 0) rr += 12;                         \
            if (rr < 8) {                                                    \
                float mn0x = 3.4e38f, mn0y = 3.4e38f, sm0x = 0.f, sm0y = 0.f;\
                float mn1x = 3.4e38f, mn1y = 3.4e38f, sm1x = 0.f, sm1y = 0.f;\
                _Pragma("unroll")                                            \
                for (int c = 0; c < 12; ++c) {                               \
                    half2v g0 = sb[bb][c][0][rr][l];                         \
                    half2v g1 = sb[bb][c][1][rr][l];                         \
                    float v0x = (float)g0[0], v0y = (float)g0[1];            \
                    float v1x = (float)g1[0], v1y = (float)g1[1];            \
                    mn0x = fminf(mn0x, v0x); sm0x += v0x;                    \
                    mn0y = fminf(mn0y, v0y); sm0y += v0y;                    \
                    mn1x = fminf(mn1x, v1x); sm1x += v1x;                    \
                    mn1y = fminf(mn1y, v1y); sm1y += v1y;                    \
                }                                                            \
                float i0x = __fdividef(1.0f, sm0x * (1.0f/12.0f) - mn0x);    \
                float i0y = __fdividef(1.0f, sm0y * (1.0f/12.0f) - mn0y);    \
                float i1x = __fdividef(1.0f, sm1x * (1.0f/12.0f) - mn1x);    \
                float i1y = __fdividef(1.0f, sm1y * (1.0f/12.0f) - mn1y);    \
                _Pragma("unroll")                                            \
                for (int c = 0; c < 12; ++c) {                               \
                    half2v g0 = sb[bb][c][0][rr][l];                         \
                    half2v g1 = sb[bb][c][1][rr][l];                         \
                    float e0x = __expf(-((float)g0[0] - mn0x) * i0x);        \
                    float e1x = __expf(-((float)g1[0] - mn1x) * i1x);        \
                    float e0y = __expf(-((float)g0[1] - mn0y) * i0y);        \
                    float e1y = __expf(-((float)g1[1] - mn1y) * i1y);        \
                    float dfx = e0x - e1x, dfy = e0y - e1y;                  \
                    acc += dfx * dfx + dfy * dfy;                            \
                }                                                            \
            }                                                                \
        }                                                                    \
    }

__global__ __launch_bounds__(768) void ffuse(const float* __restrict__ img0,
                                             const float* __restrict__ img1,
                                             float* __restrict__ partial) {
    // [buf][ch][img][row][colpair] f16x2 = 96 KB static LDS
    __shared__ half2v sb[2][NCH][2][8][64];
    __shared__ float sred[12];

    int tid = threadIdx.x;
    int wv  = tid >> 6;              // 0..11 = channel
    int l   = tid & 63;

    // hs fastest: consecutive blocks share the same d-window (L2-friendly)
    // hs: 16 slices of 8 rows; ds: 16 segs of 8 planes.
    int bx = blockIdx.x;
    int h0 = (bx & 15) << 3;
    int d0 = (bx >> 4) << 3;

    int ch = wv;
    int sd1 = c_sd1[ch], sh1 = c_sh1[ch], sw1 = c_sw1[ch];
    int sd2 = c_sd2[ch], sh2 = c_sh2[ch], sw2 = c_sw2[ch];

    // wave-uniform row byte-offsets (double clamp composed), 12 t-rows
    int rowOffA[12], rowOffB[12];
#pragma unroll
    for (int r = 0; r < 12; ++r) {
        int hq = clamp7(h0 - 2 + r);
        rowOffA[r] = clamp7(hq + sh1) * (DIM * 4);
        rowOffB[r] = clamp7(hq + sh2) * (DIM * 4);
    }

    // per-lane column byte bases (float2 at cols 2l+sw, clamped to [0,126])
    int c2 = l << 1;
    int colA = min(max(c2 + sw1, 0), 126) * 4;
    int colB = min(max(c2 + sw2, 0), 126) * 4;
    bool fixAlo = (sw1 < 0) && (l == 0);
    bool fixAhi = (sw1 > 0) && (l == 63);
    bool fixBlo = (sw2 < 0) && (l == 0);
    bool fixBhi = (sw2 > 0) && (l == 63);

    float2 win0[8], win1[8];
    half2v hist0[5][8], hist1[5][8];
#pragma unroll
    for (int k = 0; k < 8; ++k) {
        win0[k].x = 0.0f; win0[k].y = 0.0f;
        win1[k].x = 0.0f; win1[k].y = 0.0f;
#pragma unroll
        for (int s = 0; s < 5; ++s) {
            hist0[s][k] = half2v{(_Float16)0.0f, (_Float16)0.0f};
            hist1[s][k] = half2v{(_Float16)0.0f, (_Float16)0.0f};
        }
    }

    const char* im0 = (const char*)img0;
    const char* im1 = (const char*)img1;

    float acc = 0.0f;

    // 12 planes per task: s5 = it % 5 — two rings of 5, then its 10,11.
    for (int oo = 0; oo < 2; ++oo) {
#pragma unroll
        for (int j = 0; j < 5; ++j)
            PLANE_ITER(oo * 5 + j, j)
    }
    PLANE_ITER(10, 0)
    PLANE_ITER(11, 1)

    // block reduction: every wave may hold acc (rotating reducers)
#pragma unroll
    for (int off = 32; off > 0; off >>= 1)
        acc += __shfl_down(acc, off, 64);
    if (l == 0) sred[wv] = acc;
    __syncthreads();
    if (tid == 0) {
        float s = 0.0f;
#pragma unroll
        for (int w = 0; w < 12; ++w) s += sred[w];
        partial[blockIdx.x] = s;
    }
}

// kred: sum 256 partials, write the final scalar.
__global__ __launch_bounds__(256) void kred(const float* __restrict__ partial,
                                            float* __restrict__ out) {
    int tid = threadIdx.x;
    float acc = partial[tid];
#pragma unroll
    for (int off = 32; off > 0; off >>= 1)
        acc += __shfl_down(acc, off, 64);
    __shared__ float smem[4];
    int lane = tid & 63, wv = tid >> 6;
    if (lane == 0) smem[wv] = acc;
    __syncthreads();
    if (tid == 0)
        out[0] = (smem[0] + smem[1] + smem[2] + smem[3])
               * (1.0f / (12.0f * (float)VOX));
}

__global__ void kdiag(float* out, float ws_mb) { out[0] = ws_mb; }

extern "C" void kernel_launch(void* const* d_in, const int* in_sizes, int n_in,
                              void* d_out, int out_size, void* d_ws, size_t ws_size,
                              hipStream_t stream) {
    const float* y_true = (const float*)d_in[0];
    const float* y_pred = (const float*)d_in[1];
    float* out = (float*)d_out;

    const size_t NEED = 4096;
    if (ws_size < NEED) {
        kdiag<<<1, 1, 0, stream>>>(out, (float)(ws_size >> 20));
        return;
    }

    float* partial = (float*)d_ws;   // 256 floats

    // 256 blocks (16 hslices x 16 dsegs), 768 threads = 12 waves (1 ch each)
    ffuse<<<dim3(256), 768, 0, stream>>>(y_true, y_pred, partial);
    kred<<<1, 256, 0, stream>>>(partial, out);
}

// Round 11
// 193.247 us; speedup vs baseline: 1.5273x; 1.5273x over previous
//
#include <hip/hip_runtime.h>

#define DIM   128
#define DMASK 127
#define PLANE (DIM * DIM)     // 16384
#define VOX   (1 << 21)       // 128^3
#define NCH   12

typedef __attribute__((ext_vector_type(2))) _Float16 half2v;
typedef __attribute__((ext_vector_type(8))) _Float16 half8v;

// Per-channel shift pairs (d,h,w) = 2*(one_hot_idx - 1); verified (absmax 0).
__constant__ int c_sd1[12] = { 0, 0, 0, 0, 0, 2, 2, 2, 0, 0, 0, 0};
__constant__ int c_sh1[12] = { 0,-2,-2, 0, 0, 0, 0, 0, 2, 2, 2, 2};
__constant__ int c_sw1[12] = {-2, 0, 0, 2, 2, 0, 0, 0, 0, 0, 0, 0};
__constant__ int c_sd2[12] = {-2,-2, 0,-2, 0, 0, 0, 0,-2, 0, 0, 2};
__constant__ int c_sh2[12] = { 0, 0, 0, 0,-2, 0,-2, 0, 0, 0, 0, 0};
__constant__ int c_sw2[12] = { 0, 0,-2, 0, 0,-2, 0, 2, 0,-2, 2, 0};

__device__ __forceinline__ int clamp7(int v) { return min(max(v, 0), DMASK); }

// DPP wave-shift cross-lane: VALU-pipe, no DS unit; old-operand = boundary
// fix (bound_ctrl=false). HW-validated r7/r8/r9 (absmax 0.0).
__device__ __forceinline__ float dpp_shr1(float old_, float src) {
    return __int_as_float(__builtin_amdgcn_update_dpp(
        __float_as_int(old_), __float_as_int(src), 0x138, 0xF, 0xF, false));
}
__device__ __forceinline__ float dpp_shl1(float old_, float src) {
    return __int_as_float(__builtin_amdgcn_update_dpp(
        __float_as_int(old_), __float_as_int(src), 0x130, 0xF, 0xF, false));
}

// SESSION LEDGER (r0-r10):
//  - NEVER force min-waves in __launch_bounds__ (r1/r7: forced spill).
//  - 12-wave (768t) blocks: HARD VGPR ceiling 128 (waves/CU halves at 128).
//    r10: 8-row fused state (~155) "fit" per VGPR_Count=84 but spilled
//    (FETCH 246MB / WRITE 204MB). Big-row fused tiles are dead.
//  - Fused kernels pay a ~1.6x timed-vs-profiled clock tax (issue-bound at
//    67% VALUBusy; throttled when back-to-back). Unfused memory-bound
//    pipeline shows gap ~0 (r0: 68+58+3 = 131.7 timed, exact). -> UNFUSED.
//  - r5 champion: f123 68us + kmse 58us. kmse's 96MB at 1.7 TB/s is the
//    slack: 24 strided 4MB streams. THIS ROUND: channel-interleaved S
//    [voxpair][12ch][2] — f123i (12 channel-waves per block, one image per
//    block) writes 4B at stride-48B, merged in L2 by block-local temporal
//    locality (per-plane barrier bounds drift); kmse reads 96B contiguous
//    per thread (6x dwordx4).
//  - GATE: f123i WRITE_SIZE must stay 96-130MB. >>130MB = merge failed.

// F123I: r0/r5-validated per-wave pipeline (8-row x 16-plane, hist ring,
// DPP W-box), 12 channel-waves per block, one image per block.
__global__ __launch_bounds__(768) void f123i(const float* __restrict__ img0,
                                             const float* __restrict__ img1,
                                             _Float16* __restrict__ S0,
                                             _Float16* __restrict__ S1) {
    const float* img = blockIdx.y ? img1 : img0;
    _Float16* Sout   = blockIdx.y ? S1 : S0;
    const char* imgc = (const char*)img;

    int tid = threadIdx.x;
    int ch  = tid >> 6;              // 0..11 = channel (wave id)
    int l   = tid & 63;

    // 128 blocks: hs fastest (16 slices of 8 rows), ds (8 segs of 16 planes)
    int bx = blockIdx.x;
    int h0 = (bx & 15) << 3;
    int d0 = (bx >> 4) << 4;

    int sd1 = c_sd1[ch], sh1 = c_sh1[ch], sw1 = c_sw1[ch];
    int sd2 = c_sd2[ch], sh2 = c_sh2[ch], sw2 = c_sw2[ch];

    // wave-uniform row byte-offsets (double clamp composed), 12 t-rows
    int rowOffA[12], rowOffB[12];
#pragma unroll
    for (int r = 0; r < 12; ++r) {
        int hq = clamp7(h0 - 2 + r);
        rowOffA[r] = clamp7(hq + sh1) * (DIM * 4);
        rowOffB[r] = clamp7(hq + sh2) * (DIM * 4);
    }

    // per-lane column byte bases (float2 at cols 2l+sw, clamped to [0,126])
    int c2 = l << 1;
    int colA = min(max(c2 + sw1, 0), 126) * 4;
    int colB = min(max(c2 + sw2, 0), 126) * 4;
    bool fixAlo = (sw1 < 0) && (l == 0);
    bool fixAhi = (sw1 > 0) && (l == 63);
    bool fixBlo = (sw2 < 0) && (l == 0);
    bool fixBhi = (sw2 > 0) && (l == 63);

    float2 win[8];
    half2v hist[5][8];
#pragma unroll
    for (int k = 0; k < 8; ++k) {
        win[k].x = 0.0f; win[k].y = 0.0f;
#pragma unroll
        for (int s = 0; s < 5; ++s) hist[s][k] = half2v{(_Float16)0.0f, (_Float16)0.0f};
    }

    // Interleaved S: f16 index = pairIdx*24 + ch*2 (+w), pairIdx = d*8192+h*64+l.
    // Per-(k,plane) store: half2v (4B) at byte pairIdx*48 + ch*4.
    char* dstBase = (char*)Sout + ((size_t)h0 * 64 + l) * 48 + ch * 4;

    for (int oo = 0; oo < 4; ++oo) {
#pragma unroll
        for (int s5 = 0; s5 < 5; ++s5) {
            int it = oo * 5 + s5;
            int dp = clamp7(d0 - 2 + it);
            int pOffA = clamp7(dp + sd1) * (PLANE * 4);
            int pOffB = clamp7(dp + sd2) * (PLANE * 4);

            float tX[12], tY[12];
#pragma unroll
            for (int r = 0; r < 12; ++r) {
                float2 a = *(const float2*)(imgc + (pOffA + rowOffA[r] + colA));
                float2 b = *(const float2*)(imgc + (pOffB + rowOffB[r] + colB));
                a.y = fixAlo ? a.x : a.y;  a.x = fixAhi ? a.y : a.x;
                b.y = fixBlo ? b.x : b.y;  b.x = fixBhi ? b.y : b.x;
                float dx = a.x - b.x; dx *= dx;      // D2[2l]
                float dy = a.y - b.y; dy *= dy;      // D2[2l+1]
                float lx = dpp_shr1(dx, dx);         // D2[2l-2]; l0->dx
                float ly = dpp_shr1(dx, dy);         // D2[2l-1]; l0->dx
                float rx = dpp_shl1(dy, dx);         // D2[2l+2]; l63->dy
                float ry = dpp_shl1(dy, dy);         // D2[2l+3]; l63->dy
                float m = ly + dx + dy + rx;
                tX[r] = lx + m;                      // W-box(2l)
                tY[r] = m + ry;                      // W-box(2l+1)
            }

            // H-box sliding 5-row sums + D-window update + interleaved store
            float sx = tX[0] + tX[1] + tX[2] + tX[3] + tX[4];
            float sy = tY[0] + tY[1] + tY[2] + tY[3] + tY[4];
            bool dowrite = (it >= 4);
            char* dstD = dstBase + (size_t)(d0 + it - 4) * (8192 * 48);
#pragma unroll
            for (int k = 0; k < 8; ++k) {
                half2v hv = { (_Float16)sx, (_Float16)sy };  // round first (validated)
                half2v old = hist[s5][k];
                win[k].x += (float)hv[0] - (float)old[0];
                win[k].y += (float)hv[1] - (float)old[1];
                hist[s5][k] = hv;
                if (dowrite) {
                    half2v ov = { (_Float16)win[k].x, (_Float16)win[k].y };
                    *(half2v*)(dstD + k * (64 * 48)) = ov;
                }
                if (k < 7) {
                    sx += tX[k + 5] - tX[k];
                    sy += tY[k + 5] - tY[k];
                }
            }
            // drift control: keep the 12 channel-waves on the same plane so
            // their stride-48B stores coincide in L2 (full-line merge).
            __syncthreads();
        }
    }
}

// KMSE-INT: 2 vox (1 pair) per thread; 96B contiguous per thread per image
// (6x dwordx4 per thread total 192B). All-register, tiny state, 4096 blocks.
__global__ __launch_bounds__(256) void kmse(const _Float16* __restrict__ S0,
                                            const _Float16* __restrict__ S1,
                                            float* __restrict__ partial) {
    int t = blockIdx.x * 256 + threadIdx.x;       // 0..VOX/2-1

    const half8v* q0 = (const half8v*)((const char*)S0 + (size_t)t * 48);
    const half8v* q1 = (const half8v*)((const char*)S1 + (size_t)t * 48);
    half8v A0[3], A1[3];
#pragma unroll
    for (int c = 0; c < 3; ++c) A0[c] = q0[c];
#pragma unroll
    for (int c = 0; c < 3; ++c) A1[c] = q1[c];

    float mn0[2], sm0[2], mn1[2], sm1[2];
#pragma unroll
    for (int v = 0; v < 2; ++v) {
        mn0[v] = 3.4e38f; sm0[v] = 0.0f;
        mn1[v] = 3.4e38f; sm1[v] = 0.0f;
    }
#pragma unroll
    for (int c = 0; c < NCH; ++c)
#pragma unroll
        for (int v = 0; v < 2; ++v) {
            int e = c * 2 + v;
            float s0 = (float)A0[e >> 3][e & 7];
            float s1 = (float)A1[e >> 3][e & 7];
            mn0[v] = fminf(mn0[v], s0); sm0[v] += s0;
            mn1[v] = fminf(mn1[v], s1); sm1[v] += s1;
        }

    float inv0[2], inv1[2];
#pragma unroll
    for (int v = 0; v < 2; ++v) {
        inv0[v] = __fdividef(1.0f, sm0[v] * (1.0f / 12.0f) - mn0[v]);
        inv1[v] = __fdividef(1.0f, sm1[v] * (1.0f / 12.0f) - mn1[v]);
    }

    float acc = 0.0f;
#pragma unroll
    for (int c = 0; c < NCH; ++c)
#pragma unroll
        for (int v = 0; v < 2; ++v) {
            int e = c * 2 + v;
            float e0 = __expf(-((float)A0[e >> 3][e & 7] - mn0[v]) * inv0[v]);
            float e1 = __expf(-((float)A1[e >> 3][e & 7] - mn1[v]) * inv1[v]);
            float df = e0 - e1;
            acc += df * df;
        }

#pragma unroll
    for (int off = 32; off > 0; off >>= 1)
        acc += __shfl_down(acc, off, 64);
    __shared__ float smem[4];
    int lane = threadIdx.x & 63, wv = threadIdx.x >> 6;
    if (lane == 0) smem[wv] = acc;
    __syncthreads();
    if (threadIdx.x == 0)
        partial[blockIdx.x] = smem[0] + smem[1] + smem[2] + smem[3];
}

// kred: sum 4096 partials, write the final scalar.
__global__ __launch_bounds__(256) void kred(const float* __restrict__ partial,
                                            float* __restrict__ out) {
    int tid = threadIdx.x;
    float acc = 0.0f;
#pragma unroll
    for (int k = 0; k < 16; ++k)
        acc += partial[tid + (k << 8)];
#pragma unroll
    for (int off = 32; off > 0; off >>= 1)
        acc += __shfl_down(acc, off, 64);
    __shared__ float smem[4];
    int lane = tid & 63, wv = tid >> 6;
    if (lane == 0) smem[wv] = acc;
    __syncthreads();
    if (tid == 0)
        out[0] = (smem[0] + smem[1] + smem[2] + smem[3])
               * (1.0f / (12.0f * (float)VOX));
}

__global__ void kdiag(float* out, float ws_mb) { out[0] = ws_mb; }

extern "C" void kernel_launch(void* const* d_in, const int* in_sizes, int n_in,
                              void* d_out, int out_size, void* d_ws, size_t ws_size,
                              hipStream_t stream) {
    const float* y_true = (const float*)d_in[0];
    const float* y_pred = (const float*)d_in[1];
    float* out = (float*)d_out;

    const size_t SIMG = (size_t)VOX * NCH;                 // f16 per image
    const size_t NEED = 2 * SIMG * sizeof(_Float16) + 16384 + 64;  // ~96MB
    if (ws_size < NEED) {
        kdiag<<<1, 1, 0, stream>>>(out, (float)(ws_size >> 20));
        return;
    }

    _Float16* S0      = (_Float16*)d_ws;            // interleaved [pair][12][2]
    _Float16* S1      = S0 + SIMG;
    float*    partial = (float*)(S1 + SIMG);        // 4096 floats

    // 128 blocks x 2 images, 768 threads = 12 channel-waves per block
    f123i<<<dim3(128, 2), 768, 0, stream>>>(y_true, y_pred, S0, S1);
    kmse<<<VOX / 2 / 256, 256, 0, stream>>>(S0, S1, partial);
    kred<<<1, 256, 0, stream>>>(partial, out);
}

// Round 12
// 131.750 us; speedup vs baseline: 2.2402x; 1.4668x over previous
//
#include <hip/hip_runtime.h>

#define DIM   128
#define DMASK 127
#define PLANE (DIM * DIM)     // 16384
#define VOX   (1 << 21)       // 128^3
#define NCH   12

// De-aliased layout (validated): channel stride 4MB+4KB, image stride +2KB.
#define CHS   (VOX + 2048)
#define IMGS  (NCH * CHS + 1024)

typedef __attribute__((ext_vector_type(2))) _Float16 half2v;
typedef __attribute__((ext_vector_type(4))) _Float16 half4v;

// Per-channel shift pairs (d,h,w) = 2*(one_hot_idx - 1); verified (absmax 0).
__constant__ int c_sd1[12] = { 0, 0, 0, 0, 0, 2, 2, 2, 0, 0, 0, 0};
__constant__ int c_sh1[12] = { 0,-2,-2, 0, 0, 0, 0, 0, 2, 2, 2, 2};
__constant__ int c_sw1[12] = {-2, 0, 0, 2, 2, 0, 0, 0, 0, 0, 0, 0};
__constant__ int c_sd2[12] = {-2,-2, 0,-2, 0, 0, 0, 0,-2, 0, 0, 2};
__constant__ int c_sh2[12] = { 0, 0, 0, 0,-2, 0,-2, 0, 0, 0, 0, 0};
__constant__ int c_sw2[12] = { 0, 0,-2, 0, 0,-2, 0, 2, 0,-2, 2, 0};

__device__ __forceinline__ int clamp7(int v) { return min(max(v, 0), DMASK); }

// SESSION LEDGER (r0-r11):
//  - NEVER force min-waves in __launch_bounds__ (r1/r7 forced-VGPR spills).
//  - f123 (r0/r5 form): 67-68us, FETCH 23MB, WRITE=output. Both grid
//    refinements regressed (r3 HBM x2; r9 no co-residency). DO NOT TOUCH.
//  - Fused single-kernel: profiled 82 but timed ~134 (clock tax on
//    issue-bound code); geometry exhausted (r10 VGPR ceiling 128 for 12-wave
//    blocks). Dead end.
//  - r11: channel-interleaved S: write-merge worked (WRITE 100MB) but
//    scattered 4B stores cost +59us in f123i. Dead end without staging.
//  - THIS ROUND: champion pipeline + kmse LDS-staged reads. kmse v6 read
//    192MB at 3.3 TB/s with 8-B loads; 16-B loads need ~150 VGPR in-reg
//    (r4 failure) -> stage via 48KB LDS instead: 12 coalesced dwordx4
//    loads/thread -> LDS -> ds_read_b64 gather -> identical v6 math.

// F123 v5b — UNCHANGED from r5 champion (measured 67-68us x3).
__global__ __launch_bounds__(256, 3) void f123(const float* __restrict__ img0,
                                               const float* __restrict__ img1,
                                               _Float16* __restrict__ Sall) {
    const float* img = blockIdx.y ? img1 : img0;
    _Float16* outS = Sall + (size_t)blockIdx.y * IMGS;
    const char* imgc = (const char*)img;

    int wid = (blockIdx.x << 2) + (threadIdx.x >> 6);  // 0..1535
    int ch = wid >> 7;                 // 12
    int hs = (wid >> 3) & 15;          // 16 h-slices of 8 rows
    int ds = wid & 7;                  // 8 d-segs of 16 planes
    int h0 = hs << 3;
    int d0 = ds << 4;
    int l  = threadIdx.x & 63;

    int sd1 = c_sd1[ch], sh1 = c_sh1[ch], sw1 = c_sw1[ch];
    int sd2 = c_sd2[ch], sh2 = c_sh2[ch], sw2 = c_sw2[ch];

    int rowOffA[12], rowOffB[12];
#pragma unroll
    for (int r = 0; r < 12; ++r) {
        int hq = clamp7(h0 - 2 + r);
        rowOffA[r] = clamp7(hq + sh1) * (DIM * 4);
        rowOffB[r] = clamp7(hq + sh2) * (DIM * 4);
    }

    int c2 = l << 1;
    int colA = min(max(c2 + sw1, 0), 126) * 4;
    int colB = min(max(c2 + sw2, 0), 126) * 4;
    bool fixAlo = (sw1 < 0) && (l == 0);
    bool fixAhi = (sw1 > 0) && (l == 63);
    bool fixBlo = (sw2 < 0) && (l == 0);
    bool fixBhi = (sw2 > 0) && (l == 63);

    float2 win[8];
    half2v hist[5][8];
#pragma unroll
    for (int k = 0; k < 8; ++k) {
        win[k].x = 0.0f; win[k].y = 0.0f;
#pragma unroll
        for (int s = 0; s < 5; ++s) hist[s][k] = half2v{(_Float16)0.0f, (_Float16)0.0f};
    }

    _Float16* dstBase = outS + (size_t)ch * CHS + h0 * DIM + c2;

    for (int oo = 0; oo < 4; ++oo) {
#pragma unroll
        for (int s5 = 0; s5 < 5; ++s5) {
            int it = oo * 5 + s5;
            int dp = clamp7(d0 - 2 + it);
            int pOffA = clamp7(dp + sd1) * (PLANE * 4);
            int pOffB = clamp7(dp + sd2) * (PLANE * 4);

            float tX[12], tY[12];
#pragma unroll
            for (int r = 0; r < 12; ++r) {
                float2 a = *(const float2*)(imgc + (pOffA + rowOffA[r] + colA));
                float2 b = *(const float2*)(imgc + (pOffB + rowOffB[r] + colB));
                a.y = fixAlo ? a.x : a.y;  a.x = fixAhi ? a.y : a.x;
                b.y = fixBlo ? b.x : b.y;  b.x = fixBhi ? b.y : b.x;
                float dx = a.x - b.x; dx *= dx;      // D2[2l]
                float dy = a.y - b.y; dy *= dy;      // D2[2l+1]
                float lx = __shfl_up(dx, 1, 64);     // D2[2l-2]
                float ly = __shfl_up(dy, 1, 64);     // D2[2l-1]
                float rx = __shfl_down(dx, 1, 64);   // D2[2l+2]
                float ry = __shfl_down(dy, 1, 64);   // D2[2l+3]
                ly = (l == 0)  ? dx : ly;            // D2[-1 -> 0]
                rx = (l == 63) ? dy : rx;            // D2[128 -> 127]
                float m = ly + dx + dy + rx;         // shared middle
                tX[r] = lx + m;                      // W-box(2l)
                tY[r] = m + ry;                      // W-box(2l+1)
            }

            float sx = tX[0] + tX[1] + tX[2] + tX[3] + tX[4];
            float sy = tY[0] + tY[1] + tY[2] + tY[3] + tY[4];
            bool dowrite = (it >= 4);
            _Float16* dstD = dstBase + (size_t)(d0 + it - 4) * PLANE;
#pragma unroll
            for (int k = 0; k < 8; ++k) {
                half2v hv = { (_Float16)sx, (_Float16)sy };  // round first (validated)
                half2v old = hist[s5][k];
                win[k].x += (float)hv[0] - (float)old[0];
                win[k].y += (float)hv[1] - (float)old[1];
                hist[s5][k] = hv;
                if (dowrite) {
                    half2v ov = { (_Float16)win[k].x, (_Float16)win[k].y };
                    *(half2v*)(dstD + k * DIM) = ov;
                }
                if (k < 7) {
                    sx += tX[k + 5] - tX[k];
                    sy += tY[k + 5] - tY[k];
                }
            }
        }
    }
}

// KMSE v8 (r12): LDS-staged. Block = 1024 vox. Stage: 12 coalesced
// dwordx4 loads/thread (1KB/wave-instr, the 16B sweet spot) into 48KB LDS
// (24 slabs of 2KB; slab p = ch*2+img). Barrier. Gather: 24 ds_read_b64
// per thread (4 vox x 24 streams, ~48 data VGPRs). Math identical to the
// validated v6. NO min-waves bound (ledger).
__global__ __launch_bounds__(256) void kmse(const _Float16* __restrict__ S0,
                                            const _Float16* __restrict__ S1,
                                            float* __restrict__ partial) {
    __shared__ __align__(16) _Float16 sl[24][1024];   // 48 KB

    int t = threadIdx.x;
    size_t vox0 = (size_t)blockIdx.x << 10;

    // Stage: i covers slab pair {2i (threads<128), 2i+1 (threads>=128)}.
    // Within a wave p is uniform -> scalar base, lanes stride 16B.
#pragma unroll
    for (int i = 0; i < 12; ++i) {
        int p   = (t >> 7) + 2 * i;          // 0..23
        int ch  = p >> 1;
        const _Float16* Sp = (p & 1) ? S1 : S0;
        const char* src = (const char*)(Sp + (size_t)ch * CHS + vox0)
                        + (size_t)(t & 127) * 16;
        float4 v = *(const float4*)src;
        *(float4*)((char*)&sl[p][0] + (t & 127) * 16) = v;
    }
    __syncthreads();

    // Gather 4 voxels x 24 streams from LDS.
    half4v A0[NCH], A1[NCH];
#pragma unroll
    for (int ch = 0; ch < NCH; ++ch) {
        A0[ch] = *(const half4v*)((const char*)&sl[ch * 2 + 0][0] + t * 8);
        A1[ch] = *(const half4v*)((const char*)&sl[ch * 2 + 1][0] + t * 8);
    }

    // Identical math to validated v6 (4 vox/thread).
    float mn0[4], sm0[4], mn1[4], sm1[4];
#pragma unroll
    for (int j = 0; j < 4; ++j) {
        mn0[j] = 3.4e38f; sm0[j] = 0.0f;
        mn1[j] = 3.4e38f; sm1[j] = 0.0f;
    }
#pragma unroll
    for (int ch = 0; ch < NCH; ++ch)
#pragma unroll
        for (int j = 0; j < 4; ++j) {
            float s0 = (float)A0[ch][j];
            float s1 = (float)A1[ch][j];
            mn0[j] = fminf(mn0[j], s0); sm0[j] += s0;
            mn1[j] = fminf(mn1[j], s1); sm1[j] += s1;
        }

    float inv0[4], inv1[4];
#pragma unroll
    for (int j = 0; j < 4; ++j) {
        inv0[j] = __fdividef(1.0f, sm0[j] * (1.0f / 12.0f) - mn0[j]);
        inv1[j] = __fdividef(1.0f, sm1[j] * (1.0f / 12.0f) - mn1[j]);
    }

    float acc = 0.0f;
#pragma unroll
    for (int ch = 0; ch < NCH; ++ch)
#pragma unroll
        for (int j = 0; j < 4; ++j) {
            float e0 = __expf(-((float)A0[ch][j] - mn0[j]) * inv0[j]);
            float e1 = __expf(-((float)A1[ch][j] - mn1[j]) * inv1[j]);
            float df = e0 - e1;
            acc += df * df;
        }

#pragma unroll
    for (int off = 32; off > 0; off >>= 1)
        acc += __shfl_down(acc, off, 64);
    __shared__ float smem[4];
    int lane = t & 63, wv = t >> 6;
    if (lane == 0) smem[wv] = acc;
    __syncthreads();
    if (t == 0)
        partial[blockIdx.x] = smem[0] + smem[1] + smem[2] + smem[3];
}

// kred: sum 2048 partials, write the final scalar.
__global__ __launch_bounds__(256) void kred(const float* __restrict__ partial,
                                            float* __restrict__ out) {
    int tid = threadIdx.x;
    float acc = 0.0f;
#pragma unroll
    for (int k = 0; k < 8; ++k)
        acc += partial[tid + (k << 8)];
#pragma unroll
    for (int off = 32; off > 0; off >>= 1)
        acc += __shfl_down(acc, off, 64);
    __shared__ float smem[4];
    int lane = tid & 63, wv = tid >> 6;
    if (lane == 0) smem[wv] = acc;
    __syncthreads();
    if (tid == 0)
        out[0] = (smem[0] + smem[1] + smem[2] + smem[3])
               * (1.0f / (12.0f * (float)VOX));
}

__global__ void kdiag(float* out, float ws_mb) { out[0] = ws_mb; }

extern "C" void kernel_launch(void* const* d_in, const int* in_sizes, int n_in,
                              void* d_out, int out_size, void* d_ws, size_t ws_size,
                              hipStream_t stream) {
    const float* y_true = (const float*)d_in[0];
    const float* y_pred = (const float*)d_in[1];
    float* out = (float*)d_out;

    const size_t NEED = 2ull * IMGS * sizeof(_Float16) + 8192 + 64;  // ~96.2 MB
    if (ws_size < NEED) {
        kdiag<<<1, 1, 0, stream>>>(out, (float)(ws_size >> 20));
        return;
    }

    _Float16* S0      = (_Float16*)d_ws;            // ssd img0 (padded layout)
    _Float16* S1      = S0 + (size_t)IMGS;          // ssd img1
    float*    partial = (float*)(S1 + (size_t)IMGS);// 2048 floats

    // 1536 wave-tasks per image (12 ch x 16 hslices x 8 dsegs), 4 waves/block
    f123<<<dim3(384, 2), 256, 0, stream>>>(y_true, y_pred, S0);
    kmse<<<VOX / 1024, 256, 0, stream>>>(S0, S1, partial);
    kred<<<1, 256, 0, stream>>>(partial, out);
}

// Round 13
// 128.318 us; speedup vs baseline: 2.3001x; 1.0267x over previous
//
#include <hip/hip_runtime.h>

#define DIM   128
#define DMASK 127
#define PLANE (DIM * DIM)     // 16384
#define VOX   (1 << 21)       // 128^3
#define NCH   12

// De-aliased layout (validated): channel stride 4MB+4KB, image stride +2KB.
#define CHS   (VOX + 2048)
#define IMGS  (NCH * CHS + 1024)

typedef __attribute__((ext_vector_type(2))) _Float16 half2v;
typedef __attribute__((ext_vector_type(4))) _Float16 half4v;

// Per-channel shift pairs (d,h,w) = 2*(one_hot_idx - 1); verified (absmax 0).
__constant__ int c_sd1[12] = { 0, 0, 0, 0, 0, 2, 2, 2, 0, 0, 0, 0};
__constant__ int c_sh1[12] = { 0,-2,-2, 0, 0, 0, 0, 0, 2, 2, 2, 2};
__constant__ int c_sw1[12] = {-2, 0, 0, 2, 2, 0, 0, 0, 0, 0, 0, 0};
__constant__ int c_sd2[12] = {-2,-2, 0,-2, 0, 0, 0, 0,-2, 0, 0, 2};
__constant__ int c_sh2[12] = { 0, 0, 0, 0,-2, 0,-2, 0, 0, 0, 0, 0};
__constant__ int c_sw2[12] = { 0, 0,-2, 0, 0,-2, 0, 2, 0,-2, 2, 0};

__device__ __forceinline__ int clamp7(int v) { return min(max(v, 0), DMASK); }

// DPP wave-shift cross-lane: VALU-pipe (4 SIMDs), zero DS-unit ops.
// old-operand = boundary fix (bound_ctrl=false -> invalid lane keeps old).
// Mapping HW-validated r7/r8/r9/r11 (absmax 0.0, same pipeline math):
//   lx = dpp_shr1(dx, dx)  == shfl_up(dx,1)  with lane0 -> dx
//   ly = dpp_shr1(dx, dy)  == shfl_up(dy,1)  with lane0 -> dx
//   rx = dpp_shl1(dy, dx)  == shfl_down(dx,1) with lane63 -> dy
//   ry = dpp_shl1(dy, dy)  == shfl_down(dy,1) with lane63 -> dy
__device__ __forceinline__ float dpp_shr1(float old_, float src) {
    return __int_as_float(__builtin_amdgcn_update_dpp(
        __float_as_int(old_), __float_as_int(src), 0x138, 0xF, 0xF, false));
}
__device__ __forceinline__ float dpp_shl1(float old_, float src) {
    return __int_as_float(__builtin_amdgcn_update_dpp(
        __float_as_int(old_), __float_as_int(src), 0x130, 0xF, 0xF, false));
}

// SESSION LEDGER (r0-r12):
//  - NEVER force min-waves in __launch_bounds__ (r1/r7 forced-VGPR spills).
//  - f123 grid: 16-plane d-segs + (256,3) optimal (r3/r9 refinements lost).
//  - Fused single-kernel: dead end (clock tax + r10 VGPR ceiling 128).
//  - r11 interleaved-S: writer cost +59us > reader gain. Dead end.
//  - r12 kmse LDS-staging: wash vs v6 (both ~60us) -> kmse floor is the
//    24-stream HBM pattern itself, not load width. kmse v6 is final.
//  - THIS ROUND (single variable vs 129.56 champion): f123 cross-lane
//    __shfl (ds_bpermute, 48 DS ops/iter/wave, 12 waves share 1 DS unit
//    ~25-35us serialization) -> DPP wave shifts (VALU pipe, validated).

// F123 v6-dpp: r5 champion with ONLY the cross-lane ops changed to DPP.
__global__ __launch_bounds__(256, 3) void f123(const float* __restrict__ img0,
                                               const float* __restrict__ img1,
                                               _Float16* __restrict__ Sall) {
    const float* img = blockIdx.y ? img1 : img0;
    _Float16* outS = Sall + (size_t)blockIdx.y * IMGS;
    const char* imgc = (const char*)img;

    int wid = (blockIdx.x << 2) + (threadIdx.x >> 6);  // 0..1535
    int ch = wid >> 7;                 // 12
    int hs = (wid >> 3) & 15;          // 16 h-slices of 8 rows
    int ds = wid & 7;                  // 8 d-segs of 16 planes
    int h0 = hs << 3;
    int d0 = ds << 4;
    int l  = threadIdx.x & 63;

    int sd1 = c_sd1[ch], sh1 = c_sh1[ch], sw1 = c_sw1[ch];
    int sd2 = c_sd2[ch], sh2 = c_sh2[ch], sw2 = c_sw2[ch];

    int rowOffA[12], rowOffB[12];
#pragma unroll
    for (int r = 0; r < 12; ++r) {
        int hq = clamp7(h0 - 2 + r);
        rowOffA[r] = clamp7(hq + sh1) * (DIM * 4);
        rowOffB[r] = clamp7(hq + sh2) * (DIM * 4);
    }

    int c2 = l << 1;
    int colA = min(max(c2 + sw1, 0), 126) * 4;
    int colB = min(max(c2 + sw2, 0), 126) * 4;
    bool fixAlo = (sw1 < 0) && (l == 0);
    bool fixAhi = (sw1 > 0) && (l == 63);
    bool fixBlo = (sw2 < 0) && (l == 0);
    bool fixBhi = (sw2 > 0) && (l == 63);

    float2 win[8];
    half2v hist[5][8];
#pragma unroll
    for (int k = 0; k < 8; ++k) {
        win[k].x = 0.0f; win[k].y = 0.0f;
#pragma unroll
        for (int s = 0; s < 5; ++s) hist[s][k] = half2v{(_Float16)0.0f, (_Float16)0.0f};
    }

    _Float16* dstBase = outS + (size_t)ch * CHS + h0 * DIM + c2;

    for (int oo = 0; oo < 4; ++oo) {
#pragma unroll
        for (int s5 = 0; s5 < 5; ++s5) {
            int it = oo * 5 + s5;
            int dp = clamp7(d0 - 2 + it);
            int pOffA = clamp7(dp + sd1) * (PLANE * 4);
            int pOffB = clamp7(dp + sd2) * (PLANE * 4);

            float tX[12], tY[12];
#pragma unroll
            for (int r = 0; r < 12; ++r) {
                float2 a = *(const float2*)(imgc + (pOffA + rowOffA[r] + colA));
                float2 b = *(const float2*)(imgc + (pOffB + rowOffB[r] + colB));
                a.y = fixAlo ? a.x : a.y;  a.x = fixAhi ? a.y : a.x;
                b.y = fixBlo ? b.x : b.y;  b.x = fixBhi ? b.y : b.x;
                float dx = a.x - b.x; dx *= dx;      // D2[2l]
                float dy = a.y - b.y; dy *= dy;      // D2[2l+1]
                float lx = dpp_shr1(dx, dx);         // D2[2l-2]; l0->dx
                float ly = dpp_shr1(dx, dy);         // D2[2l-1]; l0->dx
                float rx = dpp_shl1(dy, dx);         // D2[2l+2]; l63->dy
                float ry = dpp_shl1(dy, dy);         // D2[2l+3]; l63->dy
                float m = ly + dx + dy + rx;         // shared middle
                tX[r] = lx + m;                      // W-box(2l)
                tY[r] = m + ry;                      // W-box(2l+1)
            }

            float sx = tX[0] + tX[1] + tX[2] + tX[3] + tX[4];
            float sy = tY[0] + tY[1] + tY[2] + tY[3] + tY[4];
            bool dowrite = (it >= 4);
            _Float16* dstD = dstBase + (size_t)(d0 + it - 4) * PLANE;
#pragma unroll
            for (int k = 0; k < 8; ++k) {
                half2v hv = { (_Float16)sx, (_Float16)sy };  // round first (validated)
                half2v old = hist[s5][k];
                win[k].x += (float)hv[0] - (float)old[0];
                win[k].y += (float)hv[1] - (float)old[1];
                hist[s5][k] = hv;
                if (dowrite) {
                    half2v ov = { (_Float16)win[k].x, (_Float16)win[k].y };
                    *(half2v*)(dstD + k * DIM) = ov;
                }
                if (k < 7) {
                    sx += tX[k + 5] - tX[k];
                    sy += tY[k + 5] - tY[k];
                }
            }
        }
    }
}

// kmse v6 (FINAL per r12: load-scheme-insensitive, ~60us structural floor).
// 4 vox/thread, 24 independent 8-B loads, all-register, no atomics.
__global__ __launch_bounds__(256, 3) void kmse(const _Float16* __restrict__ S0,
                                               const _Float16* __restrict__ S1,
                                               float* __restrict__ partial) {
    int t = blockIdx.x * 256 + threadIdx.x;       // 2048 blocks

    half4v v0[NCH], v1[NCH];
#pragma unroll
    for (int ch = 0; ch < NCH; ++ch)
        v0[ch] = ((const half4v*)(S0 + (size_t)ch * CHS))[t];
#pragma unroll
    for (int ch = 0; ch < NCH; ++ch)
        v1[ch] = ((const half4v*)(S1 + (size_t)ch * CHS))[t];

    float mn0[4], sm0[4], mn1[4], sm1[4];
#pragma unroll
    for (int j = 0; j < 4; ++j) {
        mn0[j] = 3.4e38f; sm0[j] = 0.0f;
        mn1[j] = 3.4e38f; sm1[j] = 0.0f;
    }
#pragma unroll
    for (int ch = 0; ch < NCH; ++ch)
#pragma unroll
        for (int j = 0; j < 4; ++j) {
            float s0 = (float)v0[ch][j];
            float s1 = (float)v1[ch][j];
            mn0[j] = fminf(mn0[j], s0); sm0[j] += s0;
            mn1[j] = fminf(mn1[j], s1); sm1[j] += s1;
        }

    float inv0[4], inv1[4];
#pragma unroll
    for (int j = 0; j < 4; ++j) {
        inv0[j] = __fdividef(1.0f, sm0[j] * (1.0f / 12.0f) - mn0[j]);
        inv1[j] = __fdividef(1.0f, sm1[j] * (1.0f / 12.0f) - mn1[j]);
    }

    float acc = 0.0f;
#pragma unroll
    for (int ch = 0; ch < NCH; ++ch)
#pragma unroll
        for (int j = 0; j < 4; ++j) {
            float e0 = __expf(-((float)v0[ch][j] - mn0[j]) * inv0[j]);
            float e1 = __expf(-((float)v1[ch][j] - mn1[j]) * inv1[j]);
            float df = e0 - e1;
            acc += df * df;
        }

#pragma unroll
    for (int off = 32; off > 0; off >>= 1)
        acc += __shfl_down(acc, off, 64);
    __shared__ float smem[4];
    int lane = threadIdx.x & 63, wv = threadIdx.x >> 6;
    if (lane == 0) smem[wv] = acc;
    __syncthreads();
    if (threadIdx.x == 0)
        partial[blockIdx.x] = smem[0] + smem[1] + smem[2] + smem[3];
}

// kred: sum 2048 partials, write the final scalar.
__global__ __launch_bounds__(256) void kred(const float* __restrict__ partial,
                                            float* __restrict__ out) {
    int tid = threadIdx.x;
    float acc = 0.0f;
#pragma unroll
    for (int k = 0; k < 8; ++k)
        acc += partial[tid + (k << 8)];
#pragma unroll
    for (int off = 32; off > 0; off >>= 1)
        acc += __shfl_down(acc, off, 64);
    __shared__ float smem[4];
    int lane = tid & 63, wv = tid >> 6;
    if (lane == 0) smem[wv] = acc;
    __syncthreads();
    if (tid == 0)
        out[0] = (smem[0] + smem[1] + smem[2] + smem[3])
               * (1.0f / (12.0f * (float)VOX));
}

__global__ void kdiag(float* out, float ws_mb) { out[0] = ws_mb; }

extern "C" void kernel_launch(void* const* d_in, const int* in_sizes, int n_in,
                              void* d_out, int out_size, void* d_ws, size_t ws_size,
                              hipStream_t stream) {
    const float* y_true = (const float*)d_in[0];
    const float* y_pred = (const float*)d_in[1];
    float* out = (float*)d_out;

    const size_t NEED = 2ull * IMGS * sizeof(_Float16) + 8192 + 64;  // ~96.2 MB
    if (ws_size < NEED) {
        kdiag<<<1, 1, 0, stream>>>(out, (float)(ws_size >> 20));
        return;
    }

    _Float16* S0      = (_Float16*)d_ws;            // ssd img0 (padded layout)
    _Float16* S1      = S0 + (size_t)IMGS;          // ssd img1
    float*    partial = (float*)(S1 + (size_t)IMGS);// 2048 floats

    // 1536 wave-tasks per image (12 ch x 16 hslices x 8 dsegs), 4 waves/block
    f123<<<dim3(384, 2), 256, 0, stream>>>(y_true, y_pred, S0);
    kmse<<<VOX / 4 / 256, 256, 0, stream>>>(S0, S1, partial);
    kred<<<1, 256, 0, stream>>>(partial, out);
}